// Round 3
// baseline (1805.520 us; speedup 1.0000x reference)
//
#include <hip/hip_runtime.h>
#include <hip/hip_bf16.h>
#include <stdint.h>

// DTYPE CONTRACT (R3, evidence-locked): inputs f32 (R1's bf16-read NaN'd — f32
// mantissa halves as bf16 exponents), output f32 (R2 wrote bf16 into the f32 out
// buffer; harness read word0 = [prob0|loss] bits ~= 0.498 -> err 0.1973 exactly).
// Intermediates in ws: w fp32, ea/reads bf16 (error << 1.39e-2 threshold).

#define BATCH 256
#define TLEN  500
#define DKQ   128
#define DVV   256
#define MSZ   50
#define NROWS 128000   // BATCH*TLEN

__device__ __forceinline__ float bfs(uint16_t u){
  union { uint32_t u; float f; } v; v.u = ((uint32_t)u) << 16; return v.f;
}

// =====================================================================
// K1a: w = softmax(q_e @ Mk^T) -> w_ws fp32 [row][52] (padded stride)
// 1000 blocks x 128 threads; thread = one (b,t) row. Mk staged in LDS.
// =====================================================================
__global__ __launch_bounds__(128, 1) void k_w(
    const int* __restrict__ q_data, const float* __restrict__ q_tab,
    const float* __restrict__ Mk, float* __restrict__ w_ws)
{
  __shared__ float mk[MSZ*DKQ];     // 25.6 KB
  __shared__ float wt[128*52];      // 26.6 KB
  const int tid = threadIdx.x;

  // stage Mk: 6400 floats = 1600 float4
  for (int li = tid; li < 1600; li += 128)
    ((float4*)mk)[li] = ((const float4*)Mk)[li];
  __syncthreads();

  const int row = blockIdx.x*128 + tid;
  const int qi = q_data[row];
  const float4* qrow = (const float4*)(q_tab + (size_t)qi*DKQ);

  float acc[MSZ];
  #pragma unroll
  for (int m=0;m<MSZ;m++) acc[m] = 0.f;

  #pragma unroll 1
  for (int c8=0; c8<8; c8++){        // k-chunks of 16
    float4 q0 = qrow[c8*4+0], q1 = qrow[c8*4+1], q2 = qrow[c8*4+2], q3 = qrow[c8*4+3];
    #pragma unroll
    for (int m=0;m<MSZ;m++){
      const float4* mr = (const float4*)&mk[m*DKQ + c8*16];
      float4 a = mr[0], b = mr[1], cc = mr[2], d = mr[3];
      float s = acc[m];
      s = fmaf(q0.x,a.x,s);  s = fmaf(q0.y,a.y,s);  s = fmaf(q0.z,a.z,s);  s = fmaf(q0.w,a.w,s);
      s = fmaf(q1.x,b.x,s);  s = fmaf(q1.y,b.y,s);  s = fmaf(q1.z,b.z,s);  s = fmaf(q1.w,b.w,s);
      s = fmaf(q2.x,cc.x,s); s = fmaf(q2.y,cc.y,s); s = fmaf(q2.z,cc.z,s); s = fmaf(q2.w,cc.w,s);
      s = fmaf(q3.x,d.x,s);  s = fmaf(q3.y,d.y,s);  s = fmaf(q3.z,d.z,s);  s = fmaf(q3.w,d.w,s);
      acc[m] = s;
    }
  }
  // stable softmax over 50
  float mx = acc[0];
  #pragma unroll
  for (int m=1;m<MSZ;m++) mx = fmaxf(mx, acc[m]);
  float s = 0.f;
  #pragma unroll
  for (int m=0;m<MSZ;m++){ acc[m] = __expf(acc[m]-mx); s += acc[m]; }
  float inv = 1.0f / s;
  #pragma unroll
  for (int m=0;m<MSZ;m++) wt[tid*52+m] = acc[m]*inv;
  wt[tid*52+50] = 0.f; wt[tid*52+51] = 0.f;
  __syncthreads();
  float4* dst = (float4*)(w_ws + (size_t)blockIdx.x*128*52);
  const float4* src = (const float4*)wt;
  for (int li = tid; li < 1664; li += 128) dst[li] = src[li];
}

// =====================================================================
// K1b: ea = [sigmoid(qa_e@We^T+be) | tanh(qa_e@Wa^T+ba)] -> ea_ws bf16 [row][512]
// fp32 GEMM 128000x512x256. 4000 blocks x 256 thr, 32-row tiles, K-chunk 8.
// =====================================================================
__global__ __launch_bounds__(256, 2) void k_ea(
    const int* __restrict__ qa_data, const float* __restrict__ qa_tab,
    const float* __restrict__ We, const float* __restrict__ be,
    const float* __restrict__ Wa, const float* __restrict__ ba,
    __hip_bfloat16* __restrict__ ea_ws)
{
  __shared__ float  Al[32*DVV];     // 32 KB  [row][256]
  __shared__ float4 Wl4[2*512];     // 16 KB  [kp-quad][col]
  const int tid = threadIdx.x;
  const int rb = blockIdx.x * 32;

  // stage A tile (full K): 32 rows x 64 float4, gathered + coalesced
  #pragma unroll
  for (int it=0; it<8; it++){
    int li = it*256 + tid;          // 0..2047
    int r = li >> 6, seg = li & 63;
    int idx = qa_data[rb + r];
    ((float4*)Al)[r*64 + seg] = ((const float4*)(qa_tab + (size_t)idx*DVV))[seg];
  }
  const int c = tid & 63, rg = tid >> 6, r0 = rg*8;
  float bias[8];
  #pragma unroll
  for (int j=0;j<8;j++){
    int col = c + 64*j;
    bias[j] = (col < 256) ? be[col] : ba[col-256];
  }
  float acc[8][8];
  #pragma unroll
  for (int i=0;i<8;i++){
    #pragma unroll
    for (int j=0;j<8;j++) acc[i][j]=0.f;
  }

  #pragma unroll 1
  for (int kc=0; kc<32; kc++){      // 32 chunks of 8 k
    __syncthreads();
    // stage W chunk: 512 cols x 8 floats = [2 quads][512 cols] of float4
    #pragma unroll
    for (int it=0; it<4; it++){
      int li = it*256 + tid;        // 0..1023
      int q = li >> 9, col = li & 511;
      const float* srcp = (col < 256) ? (We + (size_t)col*DVV)
                                      : (Wa + (size_t)(col-256)*DVV);
      Wl4[q*512 + col] = ((const float4*)(srcp + kc*8))[q];
    }
    __syncthreads();
    #pragma unroll
    for (int q=0; q<2; q++){
      float4 av[8], wv[8];
      #pragma unroll
      for (int i=0;i<8;i++) av[i] = *(const float4*)&Al[(r0+i)*DVV + kc*8 + q*4];
      #pragma unroll
      for (int j=0;j<8;j++) wv[j] = Wl4[q*512 + c + 64*j];
      #pragma unroll
      for (int i=0;i<8;i++){
        #pragma unroll
        for (int j=0;j<8;j++){
          float s = acc[i][j];
          s = fmaf(av[i].x, wv[j].x, s);
          s = fmaf(av[i].y, wv[j].y, s);
          s = fmaf(av[i].z, wv[j].z, s);
          s = fmaf(av[i].w, wv[j].w, s);
          acc[i][j] = s;
        }
      }
    }
  }
  // epilogue: bias + sigmoid/tanh, store bf16 (coalesced)
  #pragma unroll
  for (int i=0;i<8;i++){
    __hip_bfloat16* orow = ea_ws + (size_t)(rb + r0 + i)*512;
    #pragma unroll
    for (int j=0;j<8;j++){
      float x = acc[i][j] + bias[j];
      float v;
      if (j < 4) v = 1.f/(1.f + __expf(-x));                 // erase (sigmoid)
      else       v = 1.f - 2.f/(__expf(2.f*x) + 1.f);        // add (tanh, overflow-safe)
      orow[c + 64*j] = __float2bfloat16(v);
    }
  }
}

// =====================================================================
// K2: sequential scan. 256 blocks (one per batch) x 256 threads.
// Thread d owns Mv[0..49][d] in registers; no LDS/barriers.
// Triple-buffered register prefetch of (w, e, a, gate).
// =====================================================================
struct StepBuf {
  float4 w[13];     // 52 floats (50 used; stride-52 rows are 16B aligned)
  uint16_t e, a;
  int qv;
};

__device__ __forceinline__ void load_step(StepBuf& s, int i, int d,
    const float* __restrict__ w_ws, const uint16_t* __restrict__ ea,
    const int* __restrict__ q_data)
{
  const float4* wp = (const float4*)(w_ws + (size_t)i*52);
  #pragma unroll
  for (int q=0;q<13;q++) s.w[q] = wp[q];
  s.e = ea[(size_t)i*512 + d];
  s.a = ea[(size_t)i*512 + 256 + d];
  s.qv = q_data[i];
}

__device__ __forceinline__ float wget(const StepBuf& s, int m){
  float4 v = s.w[m>>2];
  switch (m&3){ case 0: return v.x; case 1: return v.y; case 2: return v.z; default: return v.w; }
}

__device__ __forceinline__ void do_step(const StepBuf& s, float* Mv, int i, int d,
    __hip_bfloat16* __restrict__ reads_ws)
{
  float ef = bfs(s.e), af = bfs(s.a);
  float racc[4] = {0.f,0.f,0.f,0.f};
  #pragma unroll
  for (int m=0;m<MSZ;m++) racc[m & 3] = fmaf(wget(s,m), Mv[m], racc[m & 3]);
  float rd = (racc[0]+racc[1]) + (racc[2]+racc[3]);
  if (s.qv > 0){  // write gate (block-uniform branch)
    #pragma unroll
    for (int m=0;m<MSZ;m++){
      float wm = wget(s,m);
      float om = fmaf(-wm, ef, 1.0f);   // 1 - w*e
      Mv[m] = fmaf(Mv[m], om, wm*af);
    }
  }
  reads_ws[(size_t)i*256 + d] = __float2bfloat16(rd);
}

__global__ __launch_bounds__(256, 1) void k_scan(
    const int* __restrict__ q_data, const float* __restrict__ w_ws,
    const uint16_t* __restrict__ ea_ws, const float* __restrict__ Mv0,
    __hip_bfloat16* __restrict__ reads_ws)
{
  const int b = blockIdx.x, d = threadIdx.x;
  float Mv[MSZ];
  #pragma unroll
  for (int m=0;m<MSZ;m++) Mv[m] = Mv0[m*256 + d];
  const int base = b*TLEN;
  StepBuf s0, s1, s2;
  load_step(s0, base+0, d, w_ws, ea_ws, q_data);
  load_step(s1, base+1, d, w_ws, ea_ws, q_data);
  load_step(s2, base+2, d, w_ws, ea_ws, q_data);
  #pragma unroll 1
  for (int t=0; t<498; t+=3){
    do_step(s0, Mv, base+t,   d, reads_ws);
    load_step(s0, base + (t+3 < 500 ? t+3 : 499), d, w_ws, ea_ws, q_data);
    do_step(s1, Mv, base+t+1, d, reads_ws);
    load_step(s1, base + (t+4 < 500 ? t+4 : 499), d, w_ws, ea_ws, q_data);
    do_step(s2, Mv, base+t+2, d, reads_ws);
    load_step(s2, base + (t+5 < 500 ? t+5 : 499), d, w_ws, ea_ws, q_data);
  }
  do_step(s0, Mv, base+498, d, reads_ws);
  do_step(s1, Mv, base+499, d, reads_ws);
}

// =====================================================================
// K3: h = tanh([reads|q_e]@Wr^T+br); pred=h@Wp^T+bp; probs (f32); BCE partials.
// fp32 GEMM 128000x128x384. 2000 blocks x 256 thr, 64-row tiles, K-chunk 48.
// =====================================================================
__global__ __launch_bounds__(256, 2) void k_final(
    const int* __restrict__ q_data, const float* __restrict__ q_tab,
    const uint16_t* __restrict__ reads16, const float* __restrict__ Wr,
    const float* __restrict__ br, const float* __restrict__ Wp,
    const float* __restrict__ bp, const float* __restrict__ target,
    float* __restrict__ out, float* __restrict__ parts)
{
  __shared__ float4 Af4[64*12];     // 12 KB  [row][12 k-quads of this chunk]
  __shared__ float4 WF4[12*128];    // 24 KB  [k-quad][col]
  __shared__ float redbuf[8];
  const int tid = threadIdx.x;
  const int rb = blockIdx.x * 64;
  const int c = tid & 63, rg = tid >> 6, r0 = rg*16;
  float acc0[16], acc1[16];
  #pragma unroll
  for (int i=0;i<16;i++){ acc0[i]=0.f; acc1[i]=0.f; }

  #pragma unroll 1
  for (int kc=0; kc<8; kc++){       // 8 chunks of 48 k (12 quads)
    __syncthreads();
    // stage A chunk: feat = [reads(256,bf16) | q_e(128,f32)]
    for (int li = tid; li < 64*12; li += 256){
      int row = li / 12, qd = li % 12;
      int kp0 = kc*48 + qd*4;
      float4 v;
      float* vp = (float*)&v;
      #pragma unroll
      for (int e=0;e<4;e++){
        int kpg = kp0 + e;
        if (kpg < 256) vp[e] = bfs(reads16[(size_t)(rb+row)*256 + kpg]);
        else           vp[e] = q_tab[(size_t)q_data[rb+row]*DKQ + (kpg-256)];
      }
      Af4[row*12 + qd] = v;
    }
    // stage Wr chunk: [12 quads][128 cols]
    for (int li = tid; li < 12*128; li += 256){
      int qd = li >> 7, col = li & 127;
      WF4[qd*128 + col] = ((const float4*)(Wr + (size_t)col*384 + kc*48))[qd];
    }
    __syncthreads();
    #pragma unroll
    for (int qd=0; qd<12; qd++){
      float4 w0 = WF4[qd*128 + c];
      float4 w1 = WF4[qd*128 + c + 64];
      #pragma unroll
      for (int i=0;i<16;i++){
        float4 a = Af4[(r0+i)*12 + qd];
        float s0 = acc0[i], s1 = acc1[i];
        s0 = fmaf(a.x,w0.x,s0); s0 = fmaf(a.y,w0.y,s0); s0 = fmaf(a.z,w0.z,s0); s0 = fmaf(a.w,w0.w,s0);
        s1 = fmaf(a.x,w1.x,s1); s1 = fmaf(a.y,w1.y,s1); s1 = fmaf(a.z,w1.z,s1); s1 = fmaf(a.w,w1.w,s1);
        acc0[i] = s0; acc1[i] = s1;
      }
    }
  }
  // epilogue
  float brv0 = br[c], brv1 = br[c+64];
  float wpv0 = Wp[c], wpv1 = Wp[c+64];
  float bpv  = bp[0];
  float ph[16];
  #pragma unroll
  for (int i=0;i<16;i++){
    float x0 = acc0[i] + brv0;
    float x1 = acc1[i] + brv1;
    float h0 = 1.f - 2.f/(__expf(2.f*x0)+1.f);
    float h1 = 1.f - 2.f/(__expf(2.f*x1)+1.f);
    ph[i] = h0*wpv0 + h1*wpv1;
  }
  #pragma unroll
  for (int i=0;i<16;i++){
    float v = ph[i];
    #pragma unroll
    for (int off=32; off>0; off>>=1) v += __shfl_xor(v, off);
    ph[i] = v;
  }
  float mypred = 0.f;
  #pragma unroll
  for (int i=0;i<16;i++) if (c == i) mypred = ph[i];
  float lsum = 0.f, csum = 0.f;
  if (c < 16){
    int row = rb + r0 + c;
    float pred = mypred + bpv;
    float prob = 1.f/(1.f + __expf(-pred));
    out[1 + row] = prob;                       // f32 store (the R2 bug was here)
    float tg = target[row];
    if (tg >= 0.f){
      lsum = fmaxf(pred, 0.f) - pred*tg + log1pf(__expf(-fabsf(pred)));
      csum = 1.f;
    }
  }
  #pragma unroll
  for (int off=32; off>0; off>>=1){
    lsum += __shfl_xor(lsum, off);
    csum += __shfl_xor(csum, off);
  }
  if (c == 0){ redbuf[rg*2] = lsum; redbuf[rg*2+1] = csum; }
  __syncthreads();
  if (tid == 0){
    parts[blockIdx.x]        = redbuf[0]+redbuf[2]+redbuf[4]+redbuf[6];
    parts[2000 + blockIdx.x] = redbuf[1]+redbuf[3]+redbuf[5]+redbuf[7];
  }
}

// =====================================================================
// K4: final loss reduction (deterministic, no atomics), f32 store
// =====================================================================
__global__ __launch_bounds__(256) void k_loss(
    const float* __restrict__ parts, float* __restrict__ out)
{
  __shared__ float red[8];
  const int tid = threadIdx.x;
  float l = 0.f, cn = 0.f;
  for (int i = tid; i < 2000; i += 256){ l += parts[i]; cn += parts[2000+i]; }
  #pragma unroll
  for (int off=32; off>0; off>>=1){ l += __shfl_xor(l, off); cn += __shfl_xor(cn, off); }
  if ((tid & 63) == 0){ red[(tid>>6)*2] = l; red[(tid>>6)*2+1] = cn; }
  __syncthreads();
  if (tid == 0){
    float L = red[0]+red[2]+red[4]+red[6];
    float C = red[1]+red[3]+red[5]+red[7];
    out[0] = L / fmaxf(C, 1.f);
  }
}

// =====================================================================
extern "C" void kernel_launch(void* const* d_in, const int* in_sizes, int n_in,
                              void* d_out, int out_size, void* d_ws, size_t ws_size,
                              hipStream_t stream) {
  const int*   q_data  = (const int*)d_in[0];
  const int*   qa_data = (const int*)d_in[1];
  const float* target  = (const float*)d_in[2];
  const float* q_tab   = (const float*)d_in[3];
  const float* qa_tab  = (const float*)d_in[4];
  const float* Mk  = (const float*)d_in[5];
  const float* Mv0 = (const float*)d_in[6];
  const float* We  = (const float*)d_in[7];
  const float* be  = (const float*)d_in[8];
  const float* Wa  = (const float*)d_in[9];
  const float* ba  = (const float*)d_in[10];
  const float* Wr  = (const float*)d_in[11];
  const float* br  = (const float*)d_in[12];
  const float* Wp  = (const float*)d_in[13];
  const float* bp  = (const float*)d_in[14];

  // Workspace layout (~223.25 MB, offsets 256B-aligned):
  char* ws = (char*)d_ws;
  float* w_ws = (float*)ws;                                        // 128000*52*4 = 26,624,000
  __hip_bfloat16* ea_ws    = (__hip_bfloat16*)(ws + 26624000);     // 128000*512*2 = 131,072,000
  __hip_bfloat16* reads_ws = (__hip_bfloat16*)(ws + 157696000);    // 128000*256*2 = 65,536,000
  float* parts             = (float*)(ws + 223232000);             // 4000*4 = 16,000

  float* out = (float*)d_out;   // f32: [loss, probs(128000)]

  k_w    <<<1000, 128, 0, stream>>>(q_data, q_tab, Mk, w_ws);
  k_ea   <<<4000, 256, 0, stream>>>(qa_data, qa_tab, We, be, Wa, ba, ea_ws);
  k_scan <<<256,  256, 0, stream>>>(q_data, w_ws, (const uint16_t*)ea_ws, Mv0, reads_ws);
  k_final<<<2000, 256, 0, stream>>>(q_data, q_tab, (const uint16_t*)reads_ws, Wr, br, Wp, bp, target, out, parts);
  k_loss <<<1,    256, 0, stream>>>(parts, out);
}

// Round 4
// 1592.342 us; speedup vs baseline: 1.1339x; 1.1339x over previous
//
#include <hip/hip_runtime.h>
#include <hip/hip_bf16.h>
#include <stdint.h>

// DTYPE CONTRACT (locked R3): inputs f32, output f32 [loss, probs(128000)].
// ws: w fp32 [row][52]; ea/reads bf16; qa_bf16 overlaps reads region (dead before
// k_scan writes reads); parts reuses w_ws region (dead after k_scan).

#define BATCH 256
#define TLEN  500
#define DKQ   128
#define DVV   256
#define MSZ   50
#define NROWS 128000   // BATCH*TLEN

__device__ __forceinline__ float bfs(uint16_t u){
  union { uint32_t u; float f; } v; v.u = ((uint32_t)u) << 16; return v.f;
}
__device__ __forceinline__ uint16_t f2b(float x){
  union { __hip_bfloat16 h; uint16_t u; } c; c.h = __float2bfloat16(x); return c.u;
}

// =====================================================================
// K1a: w = softmax(q_e @ Mk^T) -> w_ws fp32 [row][52]  (unchanged from R3)
// =====================================================================
__global__ __launch_bounds__(128, 1) void k_w(
    const int* __restrict__ q_data, const float* __restrict__ q_tab,
    const float* __restrict__ Mk, float* __restrict__ w_ws)
{
  __shared__ float mk[MSZ*DKQ];
  __shared__ float wt[128*52];
  const int tid = threadIdx.x;
  for (int li = tid; li < 1600; li += 128)
    ((float4*)mk)[li] = ((const float4*)Mk)[li];
  __syncthreads();

  const int row = blockIdx.x*128 + tid;
  const int qi = q_data[row];
  const float4* qrow = (const float4*)(q_tab + (size_t)qi*DKQ);

  float acc[MSZ];
  #pragma unroll
  for (int m=0;m<MSZ;m++) acc[m] = 0.f;

  #pragma unroll 1
  for (int c8=0; c8<8; c8++){
    float4 q0 = qrow[c8*4+0], q1 = qrow[c8*4+1], q2 = qrow[c8*4+2], q3 = qrow[c8*4+3];
    #pragma unroll
    for (int m=0;m<MSZ;m++){
      const float4* mr = (const float4*)&mk[m*DKQ + c8*16];
      float4 a = mr[0], b = mr[1], cc = mr[2], d = mr[3];
      float s = acc[m];
      s = fmaf(q0.x,a.x,s);  s = fmaf(q0.y,a.y,s);  s = fmaf(q0.z,a.z,s);  s = fmaf(q0.w,a.w,s);
      s = fmaf(q1.x,b.x,s);  s = fmaf(q1.y,b.y,s);  s = fmaf(q1.z,b.z,s);  s = fmaf(q1.w,b.w,s);
      s = fmaf(q2.x,cc.x,s); s = fmaf(q2.y,cc.y,s); s = fmaf(q2.z,cc.z,s); s = fmaf(q2.w,cc.w,s);
      s = fmaf(q3.x,d.x,s);  s = fmaf(q3.y,d.y,s);  s = fmaf(q3.z,d.z,s);  s = fmaf(q3.w,d.w,s);
      acc[m] = s;
    }
  }
  float mx = acc[0];
  #pragma unroll
  for (int m=1;m<MSZ;m++) mx = fmaxf(mx, acc[m]);
  float s = 0.f;
  #pragma unroll
  for (int m=0;m<MSZ;m++){ acc[m] = __expf(acc[m]-mx); s += acc[m]; }
  float inv = 1.0f / s;
  #pragma unroll
  for (int m=0;m<MSZ;m++) wt[tid*52+m] = acc[m]*inv;
  wt[tid*52+50] = 0.f; wt[tid*52+51] = 0.f;
  __syncthreads();
  float4* dst = (float4*)(w_ws + (size_t)blockIdx.x*128*52);
  const float4* src = (const float4*)wt;
  for (int li = tid; li < 1664; li += 128) dst[li] = src[li];
}

// =====================================================================
// K-cvt: qa_tab f32 -> bf16 (one-time, ~150 MB traffic)
// =====================================================================
__global__ __launch_bounds__(256) void k_cvt(
    const float* __restrict__ qa_tab, uint16_t* __restrict__ qa_bf)
{
  const size_t n4 = 6400064;   // (2*50000+1)*256 / 4
  size_t stride = (size_t)gridDim.x*blockDim.x;
  for (size_t i = (size_t)blockIdx.x*256 + threadIdx.x; i < n4; i += stride){
    float4 v = ((const float4*)qa_tab)[i];
    ushort4 o;
    o.x = f2b(v.x); o.y = f2b(v.y); o.z = f2b(v.z); o.w = f2b(v.w);
    ((ushort4*)qa_bf)[i] = o;
  }
}

// =====================================================================
// K1b: ea = [sigmoid(qa_e@We^T+be) | tanh(qa_e@Wa^T+ba)] via bf16 MFMA.
// GEMM 128000x512x256; 128x128 tiles -> 4000 blocks x 256 thr (4 waves).
// A (gathered rows) via global_load_lds w=16 from qa_bf; B staged f32->bf16.
// Fragments (verified layouts): A/B [idx=lane&15][k=(lane>>4)*8+j],
// C/D col=lane&15, row=(lane>>4)*4+reg.
// =====================================================================
typedef __attribute__((ext_vector_type(8))) short bf16x8;
typedef __attribute__((ext_vector_type(4))) float f32x4;

__device__ __forceinline__ void gl_lds16(const void* g, void* l){
  __builtin_amdgcn_global_load_lds(
      (const __attribute__((address_space(1))) void*)g,
      (__attribute__((address_space(3))) void*)l, 16, 0, 0);
}

__global__ __launch_bounds__(256, 2) void k_ea(
    const int* __restrict__ qa_data, const uint16_t* __restrict__ qa_bf,
    const float* __restrict__ We, const float* __restrict__ Wa,
    const float* __restrict__ be, const float* __restrict__ ba,
    __hip_bfloat16* __restrict__ ea_ws)
{
  __shared__ uint16_t Ab[128*32];   // 8 KB  [row][32k], 64 B row stride
  __shared__ uint16_t Bb[128*32];   // 8 KB  [col][32k]
  const int tid = threadIdx.x;
  const int lane = tid & 63, wid = tid >> 6;
  const int nb = blockIdx.x & 3, mb = blockIdx.x >> 2;   // consecutive blocks share A-tile
  const int rb = mb*128, cb = nb*128;

  // A staging: wave `wid` fills rows [wid*32, wid*32+32) as 2 issues of 16 rows.
  const char* qac = (const char*)qa_bf;
  size_t aoff0, aoff1;
  {
    int r0 = wid*32 + (lane>>2);
    aoff0 = (size_t)qa_data[rb + r0]*512      + (size_t)(lane&3)*16;
    aoff1 = (size_t)qa_data[rb + r0 + 16]*512 + (size_t)(lane&3)*16;
  }
  const float* Wsrc = (nb < 2) ? We : Wa;
  const int cb2 = (nb & 1)*128;      // col offset within Wsrc

  const int wr = (wid>>1)*64, wc = (wid&1)*64;
  float bias[4];
  #pragma unroll
  for (int tj=0;tj<4;tj++){
    int colg = cb + wc + tj*16 + (lane&15);
    bias[tj] = (nb<2) ? be[colg] : ba[colg-256];
  }

  f32x4 acc[4][4];
  #pragma unroll
  for (int i=0;i<4;i++){
    #pragma unroll
    for (int j=0;j<4;j++) acc[i][j] = (f32x4)(0.f);
  }

  #pragma unroll 1
  for (int kc=0; kc<8; kc++){
    __syncthreads();
    // A: 2 async issues per wave (each 64 lanes x 16 B = 16 rows x 64 B)
    gl_lds16(qac + aoff0 + (size_t)kc*64, &Ab[(wid*2+0)*512]);
    gl_lds16(qac + aoff1 + (size_t)kc*64, &Ab[(wid*2+1)*512]);
    // B: stage 128 cols x 32 k, f32 -> bf16
    #pragma unroll
    for (int it=0; it<4; it++){
      int li = tid*4 + it;            // 0..1023
      int col = li >> 3, kq = li & 7; // 8 float4 per col-chunk
      float4 v = ((const float4*)(Wsrc + (size_t)(cb2+col)*256 + kc*32))[kq];
      ushort4 o;
      o.x = f2b(v.x); o.y = f2b(v.y); o.z = f2b(v.z); o.w = f2b(v.w);
      *(ushort4*)&Bb[col*32 + kq*4] = o;
    }
    __syncthreads();                  // drains vmcnt (global_load_lds) + lgkm
    bf16x8 af[4], bfr[4];
    #pragma unroll
    for (int ti=0;ti<4;ti++)
      af[ti] = *(const bf16x8*)&Ab[(wr + ti*16 + (lane&15))*32 + (lane>>4)*8];
    #pragma unroll
    for (int tj=0;tj<4;tj++)
      bfr[tj] = *(const bf16x8*)&Bb[(wc + tj*16 + (lane&15))*32 + (lane>>4)*8];
    #pragma unroll
    for (int ti=0;ti<4;ti++){
      #pragma unroll
      for (int tj=0;tj<4;tj++)
        acc[ti][tj] = __builtin_amdgcn_mfma_f32_16x16x32_bf16(af[ti], bfr[tj], acc[ti][tj], 0, 0, 0);
    }
  }
  // epilogue: bias + activation (uniform per block), bf16 store
  const int rq = (lane>>4)*4, cl = lane&15;
  #pragma unroll
  for (int ti=0;ti<4;ti++){
    #pragma unroll
    for (int r=0;r<4;r++){
      int row = rb + wr + ti*16 + rq + r;
      __hip_bfloat16* orow = ea_ws + (size_t)row*512 + cb + wc;
      #pragma unroll
      for (int tj=0;tj<4;tj++){
        float x = acc[ti][tj][r] + bias[tj];
        float v = (nb<2) ? (1.f/(1.f+__expf(-x)))
                         : (1.f - 2.f/(__expf(2.f*x)+1.f));
        orow[tj*16 + cl] = __float2bfloat16(v);
      }
    }
  }
}

// =====================================================================
// K2: sequential scan, register-pipelined (forced via sched_barrier).
// 256 blocks x 256 threads; thread d owns Mv[0..49][d] in registers.
// =====================================================================
struct WRow { float4 q[13]; };

__device__ __forceinline__ void scan_load(WRow& w, uint16_t& e, uint16_t& a, int& qv,
    int i, int d, const float* __restrict__ w_ws, const uint16_t* __restrict__ ea_ws,
    const int* __restrict__ q_data)
{
  const float4* wp = (const float4*)(w_ws + (size_t)i*52);
  #pragma unroll
  for (int q=0;q<13;q++) w.q[q] = wp[q];
  e = ea_ws[(size_t)i*512 + d];
  a = ea_ws[(size_t)i*512 + 256 + d];
  qv = q_data[i];
}

__device__ __forceinline__ void scan_step(const WRow& w, uint16_t e, uint16_t a, int qv,
    float* Mv, int i, int d, __hip_bfloat16* __restrict__ reads_ws)
{
  float ef = bfs(e), af = bfs(a);
  float r0=0.f, r1=0.f, r2=0.f, r3=0.f;
  #pragma unroll
  for (int q=0;q<13;q++){
    const float4 wv = w.q[q];
    const int mb = q*4;
    r0 = fmaf(wv.x, Mv[mb], r0);
    if (mb+1<MSZ) r1 = fmaf(wv.y, Mv[mb+1], r1);
    if (mb+2<MSZ) r2 = fmaf(wv.z, Mv[mb+2], r2);
    if (mb+3<MSZ) r3 = fmaf(wv.w, Mv[mb+3], r3);
  }
  float rd = (r0+r1)+(r2+r3);
  if (qv > 0){
    #pragma unroll
    for (int q=0;q<13;q++){
      const float4 wv = w.q[q];
      const int mb = q*4;
      // Mv = Mv - w*(e*Mv - a)   (2 FMA per m)
      { float tt = fmaf(ef, Mv[mb], -af);   Mv[mb]   = fmaf(-wv.x, tt, Mv[mb]); }
      if (mb+1<MSZ){ float tt = fmaf(ef, Mv[mb+1], -af); Mv[mb+1] = fmaf(-wv.y, tt, Mv[mb+1]); }
      if (mb+2<MSZ){ float tt = fmaf(ef, Mv[mb+2], -af); Mv[mb+2] = fmaf(-wv.z, tt, Mv[mb+2]); }
      if (mb+3<MSZ){ float tt = fmaf(ef, Mv[mb+3], -af); Mv[mb+3] = fmaf(-wv.w, tt, Mv[mb+3]); }
    }
  }
  reads_ws[(size_t)i*256 + d] = __float2bfloat16(rd);
}

__global__ __launch_bounds__(256, 1) void k_scan(
    const int* __restrict__ q_data, const float* __restrict__ w_ws,
    const uint16_t* __restrict__ ea_ws, const float* __restrict__ Mv0,
    __hip_bfloat16* __restrict__ reads_ws)
{
  const int b = blockIdx.x, d = threadIdx.x;
  float Mv[MSZ];
  #pragma unroll
  for (int m=0;m<MSZ;m++) Mv[m] = Mv0[m*256 + d];
  const int base = b*TLEN;

  WRow w0, w1, w2;
  uint16_t e0,e1,e2, a0,a1,a2;
  int q0,q1,q2;
  scan_load(w0,e0,a0,q0, base+0, d, w_ws, ea_ws, q_data);
  scan_load(w1,e1,a1,q1, base+1, d, w_ws, ea_ws, q_data);
  scan_load(w2,e2,a2,q2, base+2, d, w_ws, ea_ws, q_data);
  __builtin_amdgcn_sched_barrier(0);

  #pragma unroll 1
  for (int t=0; t<498; t+=3){
    scan_step(w0,e0,a0,q0, Mv, base+t,   d, reads_ws);
    scan_load(w0,e0,a0,q0, base + (t+3 < 500 ? t+3 : 499), d, w_ws, ea_ws, q_data);
    __builtin_amdgcn_sched_barrier(0);
    scan_step(w1,e1,a1,q1, Mv, base+t+1, d, reads_ws);
    scan_load(w1,e1,a1,q1, base + (t+4 < 500 ? t+4 : 499), d, w_ws, ea_ws, q_data);
    __builtin_amdgcn_sched_barrier(0);
    scan_step(w2,e2,a2,q2, Mv, base+t+2, d, reads_ws);
    scan_load(w2,e2,a2,q2, base + (t+5 < 500 ? t+5 : 499), d, w_ws, ea_ws, q_data);
    __builtin_amdgcn_sched_barrier(0);
  }
  scan_step(w0,e0,a0,q0, Mv, base+498, d, reads_ws);
  scan_step(w1,e1,a1,q1, Mv, base+499, d, reads_ws);
}

// =====================================================================
// K3: h = tanh([reads|q_e]@Wr^T+br); pred=h@Wp^T+bp; probs f32; BCE partials.
// (unchanged from R3)
// =====================================================================
__global__ __launch_bounds__(256, 2) void k_final(
    const int* __restrict__ q_data, const float* __restrict__ q_tab,
    const uint16_t* __restrict__ reads16, const float* __restrict__ Wr,
    const float* __restrict__ br, const float* __restrict__ Wp,
    const float* __restrict__ bp, const float* __restrict__ target,
    float* __restrict__ out, float* __restrict__ parts)
{
  __shared__ float4 Af4[64*12];
  __shared__ float4 WF4[12*128];
  __shared__ float redbuf[8];
  const int tid = threadIdx.x;
  const int rb = blockIdx.x * 64;
  const int c = tid & 63, rg = tid >> 6, r0 = rg*16;
  float acc0[16], acc1[16];
  #pragma unroll
  for (int i=0;i<16;i++){ acc0[i]=0.f; acc1[i]=0.f; }

  #pragma unroll 1
  for (int kc=0; kc<8; kc++){
    __syncthreads();
    for (int li = tid; li < 64*12; li += 256){
      int row = li / 12, qd = li % 12;
      int kp0 = kc*48 + qd*4;
      float4 v;
      float* vp = (float*)&v;
      #pragma unroll
      for (int e=0;e<4;e++){
        int kpg = kp0 + e;
        if (kpg < 256) vp[e] = bfs(reads16[(size_t)(rb+row)*256 + kpg]);
        else           vp[e] = q_tab[(size_t)q_data[rb+row]*DKQ + (kpg-256)];
      }
      Af4[row*12 + qd] = v;
    }
    for (int li = tid; li < 12*128; li += 256){
      int qd = li >> 7, col = li & 127;
      WF4[qd*128 + col] = ((const float4*)(Wr + (size_t)col*384 + kc*48))[qd];
    }
    __syncthreads();
    #pragma unroll
    for (int qd=0; qd<12; qd++){
      float4 w0 = WF4[qd*128 + c];
      float4 w1 = WF4[qd*128 + c + 64];
      #pragma unroll
      for (int i=0;i<16;i++){
        float4 a = Af4[(r0+i)*12 + qd];
        float s0 = acc0[i], s1 = acc1[i];
        s0 = fmaf(a.x,w0.x,s0); s0 = fmaf(a.y,w0.y,s0); s0 = fmaf(a.z,w0.z,s0); s0 = fmaf(a.w,w0.w,s0);
        s1 = fmaf(a.x,w1.x,s1); s1 = fmaf(a.y,w1.y,s1); s1 = fmaf(a.z,w1.z,s1); s1 = fmaf(a.w,w1.w,s1);
        acc0[i] = s0; acc1[i] = s1;
      }
    }
  }
  float brv0 = br[c], brv1 = br[c+64];
  float wpv0 = Wp[c], wpv1 = Wp[c+64];
  float bpv  = bp[0];
  float ph[16];
  #pragma unroll
  for (int i=0;i<16;i++){
    float x0 = acc0[i] + brv0;
    float x1 = acc1[i] + brv1;
    float h0 = 1.f - 2.f/(__expf(2.f*x0)+1.f);
    float h1 = 1.f - 2.f/(__expf(2.f*x1)+1.f);
    ph[i] = h0*wpv0 + h1*wpv1;
  }
  #pragma unroll
  for (int i=0;i<16;i++){
    float v = ph[i];
    #pragma unroll
    for (int off=32; off>0; off>>=1) v += __shfl_xor(v, off);
    ph[i] = v;
  }
  float mypred = 0.f;
  #pragma unroll
  for (int i=0;i<16;i++) if (c == i) mypred = ph[i];
  float lsum = 0.f, csum = 0.f;
  if (c < 16){
    int row = rb + r0 + c;
    float pred = mypred + bpv;
    float prob = 1.f/(1.f + __expf(-pred));
    out[1 + row] = prob;
    float tg = target[row];
    if (tg >= 0.f){
      lsum = fmaxf(pred, 0.f) - pred*tg + log1pf(__expf(-fabsf(pred)));
      csum = 1.f;
    }
  }
  #pragma unroll
  for (int off=32; off>0; off>>=1){
    lsum += __shfl_xor(lsum, off);
    csum += __shfl_xor(csum, off);
  }
  if (c == 0){ redbuf[rg*2] = lsum; redbuf[rg*2+1] = csum; }
  __syncthreads();
  if (tid == 0){
    parts[blockIdx.x]        = redbuf[0]+redbuf[2]+redbuf[4]+redbuf[6];
    parts[2000 + blockIdx.x] = redbuf[1]+redbuf[3]+redbuf[5]+redbuf[7];
  }
}

// =====================================================================
// K4: final loss reduction (deterministic), f32 store
// =====================================================================
__global__ __launch_bounds__(256) void k_loss(
    const float* __restrict__ parts, float* __restrict__ out)
{
  __shared__ float red[8];
  const int tid = threadIdx.x;
  float l = 0.f, cn = 0.f;
  for (int i = tid; i < 2000; i += 256){ l += parts[i]; cn += parts[2000+i]; }
  #pragma unroll
  for (int off=32; off>0; off>>=1){ l += __shfl_xor(l, off); cn += __shfl_xor(cn, off); }
  if ((tid & 63) == 0){ red[(tid>>6)*2] = l; red[(tid>>6)*2+1] = cn; }
  __syncthreads();
  if (tid == 0){
    float L = red[0]+red[2]+red[4]+red[6];
    float C = red[1]+red[3]+red[5]+red[7];
    out[0] = L / fmaxf(C, 1.f);
  }
}

// =====================================================================
extern "C" void kernel_launch(void* const* d_in, const int* in_sizes, int n_in,
                              void* d_out, int out_size, void* d_ws, size_t ws_size,
                              hipStream_t stream) {
  const int*   q_data  = (const int*)d_in[0];
  const int*   qa_data = (const int*)d_in[1];
  const float* target  = (const float*)d_in[2];
  const float* q_tab   = (const float*)d_in[3];
  const float* qa_tab  = (const float*)d_in[4];
  const float* Mk  = (const float*)d_in[5];
  const float* Mv0 = (const float*)d_in[6];
  const float* We  = (const float*)d_in[7];
  const float* be  = (const float*)d_in[8];
  const float* Wa  = (const float*)d_in[9];
  const float* ba  = (const float*)d_in[10];
  const float* Wr  = (const float*)d_in[11];
  const float* br  = (const float*)d_in[12];
  const float* Wp  = (const float*)d_in[13];
  const float* bp  = (const float*)d_in[14];

  // Workspace (223,232,000 B total — proven to fit in R3):
  //  [0, 26.6M)   w_ws  (dead after k_scan -> parts reuses base)
  //  [26.6M, 157.7M) ea_ws bf16
  //  [157.7M, 223.2M) union: qa_bf16 (k_cvt->k_ea) then reads_ws (k_scan->k_final)
  char* ws = (char*)d_ws;
  float*          w_ws     = (float*)ws;
  __hip_bfloat16* ea_ws    = (__hip_bfloat16*)(ws + 26624000);
  uint16_t*       qa_bf    = (uint16_t*)(ws + 157696000);
  __hip_bfloat16* reads_ws = (__hip_bfloat16*)(ws + 157696000);
  float*          parts    = (float*)ws;            // reuses w_ws region post-scan

  float* out = (float*)d_out;   // f32: [loss, probs(128000)]

  k_w    <<<1000, 128, 0, stream>>>(q_data, q_tab, Mk, w_ws);
  k_cvt  <<<2048, 256, 0, stream>>>(qa_tab, qa_bf);
  k_ea   <<<4000, 256, 0, stream>>>(qa_data, qa_bf, We, Wa, be, ba, ea_ws);
  k_scan <<<256,  256, 0, stream>>>(q_data, w_ws, (const uint16_t*)ea_ws, Mv0, reads_ws);
  k_final<<<2000, 256, 0, stream>>>(q_data, q_tab, (const uint16_t*)reads_ws, Wr, br, Wp, bp, target, out, parts);
  k_loss <<<1,    256, 0, stream>>>(parts, out);
}

// Round 5
// 674.629 us; speedup vs baseline: 2.6763x; 2.3603x over previous
//
#include <hip/hip_runtime.h>
#include <hip/hip_bf16.h>
#include <stdint.h>

// DTYPE CONTRACT (locked R3): inputs f32, output f32 [loss, probs(128000)].
// ws: w fp32 [row][52]; ea/reads bf16; qa_bf16 overlaps reads region (dead before
// k_scan writes reads); parts reuses w_ws region (dead after k_scan).

#define BATCH 256
#define TLEN  500
#define DKQ   128
#define DVV   256
#define MSZ   50
#define NROWS 128000   // BATCH*TLEN
#define GSZ   10       // k_scan group size (500 = 50 groups of 10)

__device__ __forceinline__ float bfs(uint16_t u){
  union { uint32_t u; float f; } v; v.u = ((uint32_t)u) << 16; return v.f;
}
__device__ __forceinline__ uint16_t f2b(float x){
  union { __hip_bfloat16 h; uint16_t u; } c; c.h = __float2bfloat16(x); return c.u;
}

typedef __attribute__((ext_vector_type(8))) short bf16x8;
typedef __attribute__((ext_vector_type(4))) float f32x4;

// =====================================================================
// K1a: w = softmax(q_e @ Mk^T) -> w_ws fp32 [row][52]  (unchanged)
// =====================================================================
__global__ __launch_bounds__(128, 1) void k_w(
    const int* __restrict__ q_data, const float* __restrict__ q_tab,
    const float* __restrict__ Mk, float* __restrict__ w_ws)
{
  __shared__ float mk[MSZ*DKQ];
  __shared__ float wt[128*52];
  const int tid = threadIdx.x;
  for (int li = tid; li < 1600; li += 128)
    ((float4*)mk)[li] = ((const float4*)Mk)[li];
  __syncthreads();

  const int row = blockIdx.x*128 + tid;
  const int qi = q_data[row];
  const float4* qrow = (const float4*)(q_tab + (size_t)qi*DKQ);

  float acc[MSZ];
  #pragma unroll
  for (int m=0;m<MSZ;m++) acc[m] = 0.f;

  #pragma unroll 1
  for (int c8=0; c8<8; c8++){
    float4 q0 = qrow[c8*4+0], q1 = qrow[c8*4+1], q2 = qrow[c8*4+2], q3 = qrow[c8*4+3];
    #pragma unroll
    for (int m=0;m<MSZ;m++){
      const float4* mr = (const float4*)&mk[m*DKQ + c8*16];
      float4 a = mr[0], b = mr[1], cc = mr[2], d = mr[3];
      float s = acc[m];
      s = fmaf(q0.x,a.x,s);  s = fmaf(q0.y,a.y,s);  s = fmaf(q0.z,a.z,s);  s = fmaf(q0.w,a.w,s);
      s = fmaf(q1.x,b.x,s);  s = fmaf(q1.y,b.y,s);  s = fmaf(q1.z,b.z,s);  s = fmaf(q1.w,b.w,s);
      s = fmaf(q2.x,cc.x,s); s = fmaf(q2.y,cc.y,s); s = fmaf(q2.z,cc.z,s); s = fmaf(q2.w,cc.w,s);
      s = fmaf(q3.x,d.x,s);  s = fmaf(q3.y,d.y,s);  s = fmaf(q3.z,d.z,s);  s = fmaf(q3.w,d.w,s);
      acc[m] = s;
    }
  }
  float mx = acc[0];
  #pragma unroll
  for (int m=1;m<MSZ;m++) mx = fmaxf(mx, acc[m]);
  float s = 0.f;
  #pragma unroll
  for (int m=0;m<MSZ;m++){ acc[m] = __expf(acc[m]-mx); s += acc[m]; }
  float inv = 1.0f / s;
  #pragma unroll
  for (int m=0;m<MSZ;m++) wt[tid*52+m] = acc[m]*inv;
  wt[tid*52+50] = 0.f; wt[tid*52+51] = 0.f;
  __syncthreads();
  float4* dst = (float4*)(w_ws + (size_t)blockIdx.x*128*52);
  const float4* src = (const float4*)wt;
  for (int li = tid; li < 1664; li += 128) dst[li] = src[li];
}

// =====================================================================
// K-cvt: qa_tab f32 -> bf16 (unchanged)
// =====================================================================
__global__ __launch_bounds__(256) void k_cvt(
    const float* __restrict__ qa_tab, uint16_t* __restrict__ qa_bf)
{
  const size_t n4 = 6400064;   // (2*50000+1)*256 / 4
  size_t stride = (size_t)gridDim.x*blockDim.x;
  for (size_t i = (size_t)blockIdx.x*256 + threadIdx.x; i < n4; i += stride){
    float4 v = ((const float4*)qa_tab)[i];
    ushort4 o;
    o.x = f2b(v.x); o.y = f2b(v.y); o.z = f2b(v.z); o.w = f2b(v.w);
    ((ushort4*)qa_bf)[i] = o;
  }
}

// =====================================================================
// K1b: ea via bf16 MFMA (unchanged from R4 — verified)
// =====================================================================
__device__ __forceinline__ void gl_lds16(const void* g, void* l){
  __builtin_amdgcn_global_load_lds(
      (const __attribute__((address_space(1))) void*)g,
      (__attribute__((address_space(3))) void*)l, 16, 0, 0);
}

__global__ __launch_bounds__(256, 2) void k_ea(
    const int* __restrict__ qa_data, const uint16_t* __restrict__ qa_bf,
    const float* __restrict__ We, const float* __restrict__ Wa,
    const float* __restrict__ be, const float* __restrict__ ba,
    __hip_bfloat16* __restrict__ ea_ws)
{
  __shared__ uint16_t Ab[128*32];
  __shared__ uint16_t Bb[128*32];
  const int tid = threadIdx.x;
  const int lane = tid & 63, wid = tid >> 6;
  const int nb = blockIdx.x & 3, mb = blockIdx.x >> 2;
  const int rb = mb*128, cb = nb*128;

  const char* qac = (const char*)qa_bf;
  size_t aoff0, aoff1;
  {
    int r0 = wid*32 + (lane>>2);
    aoff0 = (size_t)qa_data[rb + r0]*512      + (size_t)(lane&3)*16;
    aoff1 = (size_t)qa_data[rb + r0 + 16]*512 + (size_t)(lane&3)*16;
  }
  const float* Wsrc = (nb < 2) ? We : Wa;
  const int cb2 = (nb & 1)*128;

  const int wr = (wid>>1)*64, wc = (wid&1)*64;
  float bias[4];
  #pragma unroll
  for (int tj=0;tj<4;tj++){
    int colg = cb + wc + tj*16 + (lane&15);
    bias[tj] = (nb<2) ? be[colg] : ba[colg-256];
  }

  f32x4 acc[4][4];
  #pragma unroll
  for (int i=0;i<4;i++){
    #pragma unroll
    for (int j=0;j<4;j++) acc[i][j] = (f32x4)(0.f);
  }

  #pragma unroll 1
  for (int kc=0; kc<8; kc++){
    __syncthreads();
    gl_lds16(qac + aoff0 + (size_t)kc*64, &Ab[(wid*2+0)*512]);
    gl_lds16(qac + aoff1 + (size_t)kc*64, &Ab[(wid*2+1)*512]);
    #pragma unroll
    for (int it=0; it<4; it++){
      int li = tid*4 + it;
      int col = li >> 3, kq = li & 7;
      float4 v = ((const float4*)(Wsrc + (size_t)(cb2+col)*256 + kc*32))[kq];
      ushort4 o;
      o.x = f2b(v.x); o.y = f2b(v.y); o.z = f2b(v.z); o.w = f2b(v.w);
      *(ushort4*)&Bb[col*32 + kq*4] = o;
    }
    __syncthreads();
    bf16x8 af[4], bfr[4];
    #pragma unroll
    for (int ti=0;ti<4;ti++)
      af[ti] = *(const bf16x8*)&Ab[(wr + ti*16 + (lane&15))*32 + (lane>>4)*8];
    #pragma unroll
    for (int tj=0;tj<4;tj++)
      bfr[tj] = *(const bf16x8*)&Bb[(wc + tj*16 + (lane&15))*32 + (lane>>4)*8];
    #pragma unroll
    for (int ti=0;ti<4;ti++){
      #pragma unroll
      for (int tj=0;tj<4;tj++)
        acc[ti][tj] = __builtin_amdgcn_mfma_f32_16x16x32_bf16(af[ti], bfr[tj], acc[ti][tj], 0, 0, 0);
    }
  }
  const int rq = (lane>>4)*4, cl = lane&15;
  #pragma unroll
  for (int ti=0;ti<4;ti++){
    #pragma unroll
    for (int r=0;r<4;r++){
      int row = rb + wr + ti*16 + rq + r;
      __hip_bfloat16* orow = ea_ws + (size_t)row*512 + cb + wc;
      #pragma unroll
      for (int tj=0;tj<4;tj++){
        float x = acc[ti][tj][r] + bias[tj];
        float v = (nb<2) ? (1.f/(1.f+__expf(-x)))
                         : (1.f - 2.f/(__expf(2.f*x)+1.f));
        orow[tj*16 + cl] = __float2bfloat16(v);
      }
    }
  }
}

// =====================================================================
// K2 v3: sequential scan. w is BLOCK-UNIFORM -> stage it in LDS,
// double-buffered in groups of 10 steps; e/a/q prefetched in registers.
// Per-step w access = same-address broadcast ds_read_b128 (conflict-free).
// =====================================================================
__global__ __launch_bounds__(256, 1) void k_scan(
    const int* __restrict__ q_data, const float* __restrict__ w_ws,
    const uint16_t* __restrict__ ea_ws, const float* __restrict__ Mv0,
    __hip_bfloat16* __restrict__ reads_ws)
{
  __shared__ float wbuf[2][GSZ*52];   // 4160 B
  const int b = blockIdx.x, d = threadIdx.x;
  float Mv[MSZ];
  #pragma unroll
  for (int m=0;m<MSZ;m++) Mv[m] = Mv0[m*256 + d];
  const int base = b*TLEN;

  float4 wreg;
  uint16_t ecur[GSZ], acur[GSZ], enxt[GSZ], anxt[GSZ];
  int qcur[GSZ], qnxt[GSZ];

  // preload group 0 (130 float4 = 10 rows x 13)
  if (d < 130) wreg = ((const float4*)(w_ws + (size_t)base*52))[d];
  #pragma unroll
  for (int j=0;j<GSZ;j++){
    ecur[j] = ea_ws[(size_t)(base+j)*512 + d];
    acur[j] = ea_ws[(size_t)(base+j)*512 + 256 + d];
    qcur[j] = q_data[base+j];
  }
  if (d < 130) ((float4*)wbuf[0])[d] = wreg;
  __syncthreads();

  #pragma unroll 1
  for (int g=0; g<50; g++){
    // prefetch group g+1 (issued before compute; consumed ~10 steps later)
    if (g < 49){
      const int sn = base + (g+1)*GSZ;
      if (d < 130) wreg = ((const float4*)(w_ws + (size_t)sn*52))[d];
      #pragma unroll
      for (int j=0;j<GSZ;j++){
        enxt[j] = ea_ws[(size_t)(sn+j)*512 + d];
        anxt[j] = ea_ws[(size_t)(sn+j)*512 + 256 + d];
        qnxt[j] = q_data[sn+j];
      }
    }
    // compute group g
    const float* wb = wbuf[g&1];
    const int s0 = base + g*GSZ;
    #pragma unroll
    for (int j=0;j<GSZ;j++){
      float4 wv[13];
      #pragma unroll
      for (int q=0;q<13;q++) wv[q] = ((const float4*)(wb + j*52))[q];
      float ef = bfs(ecur[j]), af = bfs(acur[j]);
      float r0=0.f, r1=0.f, r2=0.f, r3=0.f;
      #pragma unroll
      for (int q=0;q<13;q++){
        const int mb = q*4;
        r0 = fmaf(wv[q].x, Mv[mb], r0);
        if (mb+1<MSZ) r1 = fmaf(wv[q].y, Mv[mb+1], r1);
        if (mb+2<MSZ) r2 = fmaf(wv[q].z, Mv[mb+2], r2);
        if (mb+3<MSZ) r3 = fmaf(wv[q].w, Mv[mb+3], r3);
      }
      float rd = (r0+r1)+(r2+r3);
      reads_ws[(size_t)(s0+j)*256 + d] = __float2bfloat16(rd);
      if (qcur[j] > 0){   // block-uniform branch
        #pragma unroll
        for (int q=0;q<13;q++){
          const int mb = q*4;
          // Mv = Mv - w*(e*Mv - a)  (2 FMA per m)
          { float tt = fmaf(ef, Mv[mb], -af);   Mv[mb]   = fmaf(-wv[q].x, tt, Mv[mb]); }
          if (mb+1<MSZ){ float tt = fmaf(ef, Mv[mb+1], -af); Mv[mb+1] = fmaf(-wv[q].y, tt, Mv[mb+1]); }
          if (mb+2<MSZ){ float tt = fmaf(ef, Mv[mb+2], -af); Mv[mb+2] = fmaf(-wv[q].z, tt, Mv[mb+2]); }
          if (mb+3<MSZ){ float tt = fmaf(ef, Mv[mb+3], -af); Mv[mb+3] = fmaf(-wv[q].w, tt, Mv[mb+3]); }
        }
      }
    }
    // stage group g+1 into the other buffer; single barrier per group
    if (g < 49){
      if (d < 130) ((float4*)wbuf[(g+1)&1])[d] = wreg;
      #pragma unroll
      for (int j=0;j<GSZ;j++){ ecur[j]=enxt[j]; acur[j]=anxt[j]; qcur[j]=qnxt[j]; }
    }
    __syncthreads();
  }
}

// =====================================================================
// K3 v2: bf16 MFMA. h = tanh([reads|q_e]@Wr^T+br); pred=h@Wp^T+bp;
// probs f32; BCE partials. GEMM 128000x128x384, 64-row tiles, K-chunk 32.
// Per wave: 16 rows x 128 cols (8 col-tiles of 16).
// =====================================================================
__global__ __launch_bounds__(256, 2) void k_final(
    const int* __restrict__ q_data, const float* __restrict__ q_tab,
    const uint16_t* __restrict__ reads16, const float* __restrict__ Wr,
    const float* __restrict__ br, const float* __restrict__ Wp,
    const float* __restrict__ bp, const float* __restrict__ target,
    float* __restrict__ out, float* __restrict__ parts)
{
  __shared__ uint16_t Ab[64*32];    // 4 KB
  __shared__ uint16_t Bb[128*32];   // 8 KB
  __shared__ float redbuf[8];
  const int tid = threadIdx.x;
  const int lane = tid & 63, wid = tid >> 6;
  const int rb = blockIdx.x * 64;

  f32x4 acc[8];
  #pragma unroll
  for (int tj=0;tj<8;tj++) acc[tj] = (f32x4)(0.f);

  #pragma unroll 1
  for (int kc=0; kc<12; kc++){
    __syncthreads();
    if (kc < 8){
      // A from reads16 (already bf16): 64 rows x 32 u16; one uint4 (8 u16)/thread
      int row = tid >> 2, seg = tid & 3;
      *(uint4*)&Ab[row*32 + seg*8] =
        *(const uint4*)&reads16[(size_t)(rb+row)*256 + kc*32 + seg*8];
    } else {
      // A from q_tab (f32 -> bf16): 64 rows x 32 f; 2 float4/thread
      #pragma unroll
      for (int it=0; it<2; it++){
        int li = it*256 + tid;
        int row = li >> 3, seg = li & 7;
        float4 v = *(const float4*)&q_tab[(size_t)q_data[rb+row]*DKQ + (kc-8)*32 + seg*4];
        ushort4 o; o.x=f2b(v.x); o.y=f2b(v.y); o.z=f2b(v.z); o.w=f2b(v.w);
        *(ushort4*)&Ab[row*32 + seg*4] = o;
      }
    }
    // B from Wr (f32 -> bf16): 128 cols x 32 k; 4 float4/thread
    #pragma unroll
    for (int it=0; it<4; it++){
      int li = it*256 + tid;
      int col = li >> 3, seg = li & 7;
      float4 v = *(const float4*)&Wr[(size_t)col*384 + kc*32 + seg*4];
      ushort4 o; o.x=f2b(v.x); o.y=f2b(v.y); o.z=f2b(v.z); o.w=f2b(v.w);
      *(ushort4*)&Bb[col*32 + seg*4] = o;
    }
    __syncthreads();
    bf16x8 af = *(const bf16x8*)&Ab[(wid*16 + (lane&15))*32 + (lane>>4)*8];
    #pragma unroll
    for (int tj=0;tj<8;tj++){
      bf16x8 bf = *(const bf16x8*)&Bb[(tj*16 + (lane&15))*32 + (lane>>4)*8];
      acc[tj] = __builtin_amdgcn_mfma_f32_16x16x32_bf16(af, bf, acc[tj], 0, 0, 0);
    }
  }
  // epilogue: h=tanh(.+br), partial pred = h*Wp, reduce over cols
  const int cl = lane & 15, rq = lane >> 4;
  float p[4] = {0.f,0.f,0.f,0.f};
  #pragma unroll
  for (int tj=0;tj<8;tj++){
    int cg = tj*16 + cl;
    float brv = br[cg], wpv = Wp[cg];
    #pragma unroll
    for (int r=0;r<4;r++){
      float x = acc[tj][r] + brv;
      float h = 1.f - 2.f/(__expf(2.f*x)+1.f);
      p[r] = fmaf(h, wpv, p[r]);
    }
  }
  #pragma unroll
  for (int off=1; off<16; off<<=1){
    #pragma unroll
    for (int r=0;r<4;r++) p[r] += __shfl_xor(p[r], off);
  }
  float bpv = bp[0];
  float lsum = 0.f, csum = 0.f;
  if (cl == 0){
    #pragma unroll
    for (int r=0;r<4;r++){
      int row = rb + wid*16 + rq*4 + r;
      float pred = p[r] + bpv;
      out[1 + row] = 1.f/(1.f + __expf(-pred));
      float tg = target[row];
      if (tg >= 0.f){
        lsum += fmaxf(pred, 0.f) - pred*tg + log1pf(__expf(-fabsf(pred)));
        csum += 1.f;
      }
    }
  }
  #pragma unroll
  for (int off=16; off<64; off<<=1){
    lsum += __shfl_xor(lsum, off);
    csum += __shfl_xor(csum, off);
  }
  if (lane == 0){ redbuf[wid*2] = lsum; redbuf[wid*2+1] = csum; }
  __syncthreads();
  if (tid == 0){
    parts[blockIdx.x]        = redbuf[0]+redbuf[2]+redbuf[4]+redbuf[6];
    parts[2000 + blockIdx.x] = redbuf[1]+redbuf[3]+redbuf[5]+redbuf[7];
  }
}

// =====================================================================
// K4: final loss reduction (unchanged)
// =====================================================================
__global__ __launch_bounds__(256) void k_loss(
    const float* __restrict__ parts, float* __restrict__ out)
{
  __shared__ float red[8];
  const int tid = threadIdx.x;
  float l = 0.f, cn = 0.f;
  for (int i = tid; i < 2000; i += 256){ l += parts[i]; cn += parts[2000+i]; }
  #pragma unroll
  for (int off=32; off>0; off>>=1){ l += __shfl_xor(l, off); cn += __shfl_xor(cn, off); }
  if ((tid & 63) == 0){ red[(tid>>6)*2] = l; red[(tid>>6)*2+1] = cn; }
  __syncthreads();
  if (tid == 0){
    float L = red[0]+red[2]+red[4]+red[6];
    float C = red[1]+red[3]+red[5]+red[7];
    out[0] = L / fmaxf(C, 1.f);
  }
}

// =====================================================================
extern "C" void kernel_launch(void* const* d_in, const int* in_sizes, int n_in,
                              void* d_out, int out_size, void* d_ws, size_t ws_size,
                              hipStream_t stream) {
  const int*   q_data  = (const int*)d_in[0];
  const int*   qa_data = (const int*)d_in[1];
  const float* target  = (const float*)d_in[2];
  const float* q_tab   = (const float*)d_in[3];
  const float* qa_tab  = (const float*)d_in[4];
  const float* Mk  = (const float*)d_in[5];
  const float* Mv0 = (const float*)d_in[6];
  const float* We  = (const float*)d_in[7];
  const float* be  = (const float*)d_in[8];
  const float* Wa  = (const float*)d_in[9];
  const float* ba  = (const float*)d_in[10];
  const float* Wr  = (const float*)d_in[11];
  const float* br  = (const float*)d_in[12];
  const float* Wp  = (const float*)d_in[13];
  const float* bp  = (const float*)d_in[14];

  // Workspace (223,232,000 B total):
  //  [0, 26.6M)       w_ws (dead after k_scan -> parts reuses base)
  //  [26.6M, 157.7M)  ea_ws bf16
  //  [157.7M, 223.2M) union: qa_bf16 (k_cvt->k_ea) then reads_ws (k_scan->k_final)
  char* ws = (char*)d_ws;
  float*          w_ws     = (float*)ws;
  __hip_bfloat16* ea_ws    = (__hip_bfloat16*)(ws + 26624000);
  uint16_t*       qa_bf    = (uint16_t*)(ws + 157696000);
  __hip_bfloat16* reads_ws = (__hip_bfloat16*)(ws + 157696000);
  float*          parts    = (float*)ws;

  float* out = (float*)d_out;   // f32: [loss, probs(128000)]

  k_w    <<<1000, 128, 0, stream>>>(q_data, q_tab, Mk, w_ws);
  k_cvt  <<<2048, 256, 0, stream>>>(qa_tab, qa_bf);
  k_ea   <<<4000, 256, 0, stream>>>(qa_data, qa_bf, We, Wa, be, ba, ea_ws);
  k_scan <<<256,  256, 0, stream>>>(q_data, w_ws, (const uint16_t*)ea_ws, Mv0, reads_ws);
  k_final<<<2000, 256, 0, stream>>>(q_data, q_tab, (const uint16_t*)reads_ws, Wr, br, Wp, bp, target, out, parts);
  k_loss <<<1,    256, 0, stream>>>(parts, out);
}

// Round 6
// 653.021 us; speedup vs baseline: 2.7649x; 1.0331x over previous
//
#include <hip/hip_runtime.h>
#include <hip/hip_bf16.h>
#include <stdint.h>

// DTYPE CONTRACT (locked R3): inputs f32, output f32 [loss, probs(128000)].
// WS MAP (223,248,000 B budget proven R3):
//   [0, 26.6M)        w_ws fp32 [row][52]  (k_w -> k_scan); after k_scan dead:
//                       parts @ +0 (16KB), wr_bf @ +16.0M, q_bf @ +2.0M (k_cvt2 -> k_final)
//   [26.6M, 157.7M)   ea_ws bf16 [row][512] (k_ea -> k_scan)
//   [157.7M, 223.2M)  union: qa_bf (51.2M) + Wcomb bf16 (256KB) (k_cvt -> k_ea),
//                     then reads_ws bf16 (k_scan -> k_final)

#define BATCH 256
#define TLEN  500
#define DKQ   128
#define DVV   256
#define MSZ   50
#define NROWS 128000
#define GSZ   10

__device__ __forceinline__ float bfs(uint16_t u){
  union { uint32_t u; float f; } v; v.u = ((uint32_t)u) << 16; return v.f;
}
__device__ __forceinline__ uint16_t f2b(float x){
  union { __hip_bfloat16 h; uint16_t u; } c; c.h = __float2bfloat16(x); return c.u;
}

typedef __attribute__((ext_vector_type(8))) short bf16x8;
typedef __attribute__((ext_vector_type(4))) float f32x4;

__device__ __forceinline__ void gl_lds16(const void* g, void* l){
  __builtin_amdgcn_global_load_lds(
      (const __attribute__((address_space(1))) void*)g,
      (__attribute__((address_space(3))) void*)l, 16, 0, 0);
}

// =====================================================================
// K1a: w = softmax(q_e @ Mk^T) -> w_ws fp32 [row][52]  (unchanged)
// =====================================================================
__global__ __launch_bounds__(128, 1) void k_w(
    const int* __restrict__ q_data, const float* __restrict__ q_tab,
    const float* __restrict__ Mk, float* __restrict__ w_ws)
{
  __shared__ float mk[MSZ*DKQ];
  __shared__ float wt[128*52];
  const int tid = threadIdx.x;
  for (int li = tid; li < 1600; li += 128)
    ((float4*)mk)[li] = ((const float4*)Mk)[li];
  __syncthreads();

  const int row = blockIdx.x*128 + tid;
  const int qi = q_data[row];
  const float4* qrow = (const float4*)(q_tab + (size_t)qi*DKQ);

  float acc[MSZ];
  #pragma unroll
  for (int m=0;m<MSZ;m++) acc[m] = 0.f;

  #pragma unroll 1
  for (int c8=0; c8<8; c8++){
    float4 q0 = qrow[c8*4+0], q1 = qrow[c8*4+1], q2 = qrow[c8*4+2], q3 = qrow[c8*4+3];
    #pragma unroll
    for (int m=0;m<MSZ;m++){
      const float4* mr = (const float4*)&mk[m*DKQ + c8*16];
      float4 a = mr[0], b = mr[1], cc = mr[2], d = mr[3];
      float s = acc[m];
      s = fmaf(q0.x,a.x,s);  s = fmaf(q0.y,a.y,s);  s = fmaf(q0.z,a.z,s);  s = fmaf(q0.w,a.w,s);
      s = fmaf(q1.x,b.x,s);  s = fmaf(q1.y,b.y,s);  s = fmaf(q1.z,b.z,s);  s = fmaf(q1.w,b.w,s);
      s = fmaf(q2.x,cc.x,s); s = fmaf(q2.y,cc.y,s); s = fmaf(q2.z,cc.z,s); s = fmaf(q2.w,cc.w,s);
      s = fmaf(q3.x,d.x,s);  s = fmaf(q3.y,d.y,s);  s = fmaf(q3.z,d.z,s);  s = fmaf(q3.w,d.w,s);
      acc[m] = s;
    }
  }
  float mx = acc[0];
  #pragma unroll
  for (int m=1;m<MSZ;m++) mx = fmaxf(mx, acc[m]);
  float s = 0.f;
  #pragma unroll
  for (int m=0;m<MSZ;m++){ acc[m] = __expf(acc[m]-mx); s += acc[m]; }
  float inv = 1.0f / s;
  #pragma unroll
  for (int m=0;m<MSZ;m++) wt[tid*52+m] = acc[m]*inv;
  wt[tid*52+50] = 0.f; wt[tid*52+51] = 0.f;   // zero pad -> masking-free k_scan
  __syncthreads();
  float4* dst = (float4*)(w_ws + (size_t)blockIdx.x*128*52);
  const float4* src = (const float4*)wt;
  for (int li = tid; li < 1664; li += 128) dst[li] = src[li];
}

// =====================================================================
// K-cvt: qa_tab f32 -> bf16  AND  Wcomb = [We|Wa] f32 -> bf16
// =====================================================================
__global__ __launch_bounds__(256) void k_cvt(
    const float* __restrict__ qa_tab, const float* __restrict__ We,
    const float* __restrict__ Wa, uint16_t* __restrict__ qa_bf,
    uint16_t* __restrict__ wcomb)
{
  const size_t n_qa4 = 6400064;            // 100001*256/4
  const size_t n_w4  = 32768;              // 512*256/4
  size_t stride = (size_t)gridDim.x*blockDim.x;
  for (size_t i = (size_t)blockIdx.x*256 + threadIdx.x; i < n_qa4 + n_w4; i += stride){
    float4 v;
    if (i < n_qa4){
      v = ((const float4*)qa_tab)[i];
      ushort4 o; o.x=f2b(v.x); o.y=f2b(v.y); o.z=f2b(v.z); o.w=f2b(v.w);
      ((ushort4*)qa_bf)[i] = o;
    } else {
      size_t j = i - n_qa4;                // float4 index into Wcomb [512][256]
      size_t f = j*4;
      int col = (int)(f >> 8), k = (int)(f & 255);
      const float* srcp = (col < 256) ? (We + (size_t)col*256 + k)
                                      : (Wa + (size_t)(col-256)*256 + k);
      v = *(const float4*)srcp;
      ushort4 o; o.x=f2b(v.x); o.y=f2b(v.y); o.z=f2b(v.z); o.w=f2b(v.w);
      ((ushort4*)wcomb)[j] = o;
    }
  }
}

// =====================================================================
// K-cvt2 (after k_scan, into dead w_ws region): q_tab -> q_bf, Wr -> wr_bf
// =====================================================================
__global__ __launch_bounds__(256) void k_cvt2(
    const float* __restrict__ q_tab, const float* __restrict__ Wr,
    uint16_t* __restrict__ q_bf, uint16_t* __restrict__ wr_bf)
{
  const size_t n_q4  = 1600032;            // 50001*128/4
  const size_t n_wr4 = 12288;              // 128*384/4
  size_t stride = (size_t)gridDim.x*blockDim.x;
  for (size_t i = (size_t)blockIdx.x*256 + threadIdx.x; i < n_q4 + n_wr4; i += stride){
    if (i < n_q4){
      float4 v = ((const float4*)q_tab)[i];
      ushort4 o; o.x=f2b(v.x); o.y=f2b(v.y); o.z=f2b(v.z); o.w=f2b(v.w);
      ((ushort4*)q_bf)[i] = o;
    } else {
      size_t j = i - n_q4;
      float4 v = ((const float4*)Wr)[j];
      ushort4 o; o.x=f2b(v.x); o.y=f2b(v.y); o.z=f2b(v.z); o.w=f2b(v.w);
      ((ushort4*)wr_bf)[j] = o;
    }
  }
}

// =====================================================================
// K1b: ea via bf16 MFMA; all staging via global_load_lds (zero staging VALU).
// XCD-sibling swizzle: 4 blocks sharing an A-tile land on the same XCD.
// =====================================================================
__global__ __launch_bounds__(256, 2) void k_ea(
    const int* __restrict__ qa_data, const uint16_t* __restrict__ qa_bf,
    const uint16_t* __restrict__ wcomb, const float* __restrict__ be,
    const float* __restrict__ ba, __hip_bfloat16* __restrict__ ea_ws)
{
  __shared__ uint16_t Ab[128*32];
  __shared__ uint16_t Bb[128*32];
  const int tid = threadIdx.x;
  const int lane = tid & 63, wid = tid >> 6;
  const int braw = blockIdx.x;
  const int nb = (braw >> 3) & 3;                      // col-block
  const int mb = (braw & 7) | ((braw >> 5) << 3);      // row-block; siblings: b,b+8,b+16,b+24 -> same XCD (b%8)
  const int rb = mb*128, cb = nb*128;

  const char* qac = (const char*)qa_bf;
  size_t aoff0, aoff1;
  {
    int r0 = wid*32 + (lane>>2);
    aoff0 = (size_t)qa_data[rb + r0]*512      + (size_t)(lane&3)*16;
    aoff1 = (size_t)qa_data[rb + r0 + 16]*512 + (size_t)(lane&3)*16;
  }
  const char* wcb = (const char*)wcomb;
  size_t boff0 = (size_t)(cb + wid*32 + (lane>>2))*512 + (size_t)(lane&3)*16;
  size_t boff1 = boff0 + 16*512;

  const int wr = (wid>>1)*64, wc = (wid&1)*64;
  float bias[4];
  #pragma unroll
  for (int tj=0;tj<4;tj++){
    int colg = cb + wc + tj*16 + (lane&15);
    bias[tj] = (nb<2) ? be[colg] : ba[colg-256];
  }

  f32x4 acc[4][4];
  #pragma unroll
  for (int i=0;i<4;i++){
    #pragma unroll
    for (int j=0;j<4;j++) acc[i][j] = (f32x4)(0.f);
  }

  #pragma unroll 1
  for (int kc=0; kc<8; kc++){
    __syncthreads();
    gl_lds16(qac + aoff0 + (size_t)kc*64, &Ab[(wid*2+0)*512]);
    gl_lds16(qac + aoff1 + (size_t)kc*64, &Ab[(wid*2+1)*512]);
    gl_lds16(wcb + boff0 + (size_t)kc*64, &Bb[(wid*2+0)*512]);
    gl_lds16(wcb + boff1 + (size_t)kc*64, &Bb[(wid*2+1)*512]);
    __syncthreads();
    bf16x8 af[4], bfr[4];
    #pragma unroll
    for (int ti=0;ti<4;ti++)
      af[ti] = *(const bf16x8*)&Ab[(wr + ti*16 + (lane&15))*32 + (lane>>4)*8];
    #pragma unroll
    for (int tj=0;tj<4;tj++)
      bfr[tj] = *(const bf16x8*)&Bb[(wc + tj*16 + (lane&15))*32 + (lane>>4)*8];
    #pragma unroll
    for (int ti=0;ti<4;ti++){
      #pragma unroll
      for (int tj=0;tj<4;tj++)
        acc[ti][tj] = __builtin_amdgcn_mfma_f32_16x16x32_bf16(af[ti], bfr[tj], acc[ti][tj], 0, 0, 0);
    }
  }
  const int rq = (lane>>4)*4, cl = lane&15;
  #pragma unroll
  for (int ti=0;ti<4;ti++){
    #pragma unroll
    for (int r=0;r<4;r++){
      int row = rb + wr + ti*16 + rq + r;
      __hip_bfloat16* orow = ea_ws + (size_t)row*512 + cb + wc;
      #pragma unroll
      for (int tj=0;tj<4;tj++){
        float x = acc[ti][tj][r] + bias[tj];
        float v = (nb<2) ? (1.f/(1.f+__expf(-x)))
                         : (1.f - 2.f/(__expf(2.f*x)+1.f));
        orow[tj*16 + cl] = __float2bfloat16(v);
      }
    }
  }
}

// =====================================================================
// K2 v4: split-m scan. 256 blocks x 512 threads (8 waves -> 2 waves/SIMD).
// Thread (d = tid&255, h = tid>>8): h0 owns even w-quads (+quad12), h1 odd.
// Per-step partial-sum exchange via double-buffered LDS (1 barrier/step).
// w block-uniform in LDS (double-buffered groups of 10); e/a/q in registers.
// =====================================================================
__global__ __launch_bounds__(512, 1) void k_scan(
    const int* __restrict__ q_data, const float* __restrict__ w_ws,
    const uint16_t* __restrict__ ea_ws, const float* __restrict__ Mv0,
    __hip_bfloat16* __restrict__ reads_ws)
{
  __shared__ float wbuf[2][GSZ*52];   // 4160 B
  __shared__ float part[2][256];      // 2048 B
  const int tid = threadIdx.x;
  const int d = tid & 255, h = tid >> 8;
  const int base = blockIdx.x*TLEN;

  // Mv: local qq -> global quad 2*qq+h; pads zero (w pads are zero too)
  float Mv[28];
  #pragma unroll
  for (int qq=0; qq<7; qq++){
    #pragma unroll
    for (int e=0;e<4;e++){
      int quad = 2*qq + h, m = quad*4 + e;
      Mv[qq*4+e] = (quad <= 12 && m < MSZ) ? Mv0[m*256 + d] : 0.f;
    }
  }

  float4 wreg;
  uint16_t ecur[GSZ], acur[GSZ], enxt[GSZ], anxt[GSZ];
  int qcur[GSZ], qnxt[GSZ];

  if (tid < 130) wreg = ((const float4*)(w_ws + (size_t)base*52))[tid];
  #pragma unroll
  for (int j=0;j<GSZ;j++){
    ecur[j] = ea_ws[(size_t)(base+j)*512 + d];
    acur[j] = ea_ws[(size_t)(base+j)*512 + 256 + d];
    qcur[j] = q_data[base+j];
  }
  if (tid < 130) ((float4*)wbuf[0])[tid] = wreg;
  __syncthreads();

  #pragma unroll 1
  for (int g=0; g<50; g++){
    if (g < 49){
      const int sn = base + (g+1)*GSZ;
      if (tid < 130) wreg = ((const float4*)(w_ws + (size_t)sn*52))[tid];
      #pragma unroll
      for (int j=0;j<GSZ;j++){
        enxt[j] = ea_ws[(size_t)(sn+j)*512 + d];
        anxt[j] = ea_ws[(size_t)(sn+j)*512 + 256 + d];
        qnxt[j] = q_data[sn+j];
      }
    }
    const float* wb = wbuf[g&1];
    const int s0 = base + g*GSZ;
    #pragma unroll
    for (int j=0;j<GSZ;j++){
      const float4* wq = (const float4*)(wb + j*52);
      float ef = bfs(ecur[j]), af = bfs(acur[j]);
      float4 wv[7];
      #pragma unroll
      for (int qq=0; qq<6; qq++) wv[qq] = wq[2*qq + h];
      if (h == 0) wv[6] = wq[12];
      float r0=0.f, r1=0.f, r2=0.f, r3=0.f;
      #pragma unroll
      for (int qq=0; qq<6; qq++){
        r0 = fmaf(wv[qq].x, Mv[qq*4+0], r0);
        r1 = fmaf(wv[qq].y, Mv[qq*4+1], r1);
        r2 = fmaf(wv[qq].z, Mv[qq*4+2], r2);
        r3 = fmaf(wv[qq].w, Mv[qq*4+3], r3);
      }
      if (h == 0){
        r0 = fmaf(wv[6].x, Mv[24], r0);
        r1 = fmaf(wv[6].y, Mv[25], r1);
        r2 = fmaf(wv[6].z, Mv[26], r2);   // zero-pad lanes
        r3 = fmaf(wv[6].w, Mv[27], r3);
      }
      float rp = (r0+r1)+(r2+r3);
      if (h == 0) part[j&1][d] = rp;
      __syncthreads();
      if (h == 1){
        float rd = rp + part[j&1][d];
        reads_ws[(size_t)(s0+j)*256 + d] = __float2bfloat16(rd);
      }
      if (qcur[j] > 0){   // block-uniform branch
        #pragma unroll
        for (int qq=0; qq<6; qq++){
          { float tt = fmaf(ef, Mv[qq*4+0], -af); Mv[qq*4+0] = fmaf(-wv[qq].x, tt, Mv[qq*4+0]); }
          { float tt = fmaf(ef, Mv[qq*4+1], -af); Mv[qq*4+1] = fmaf(-wv[qq].y, tt, Mv[qq*4+1]); }
          { float tt = fmaf(ef, Mv[qq*4+2], -af); Mv[qq*4+2] = fmaf(-wv[qq].z, tt, Mv[qq*4+2]); }
          { float tt = fmaf(ef, Mv[qq*4+3], -af); Mv[qq*4+3] = fmaf(-wv[qq].w, tt, Mv[qq*4+3]); }
        }
        if (h == 0){
          { float tt = fmaf(ef, Mv[24], -af); Mv[24] = fmaf(-wv[6].x, tt, Mv[24]); }
          { float tt = fmaf(ef, Mv[25], -af); Mv[25] = fmaf(-wv[6].y, tt, Mv[25]); }
        }
      }
    }
    if (g < 49){
      if (tid < 130) ((float4*)wbuf[(g+1)&1])[tid] = wreg;
      #pragma unroll
      for (int j=0;j<GSZ;j++){ ecur[j]=enxt[j]; acur[j]=anxt[j]; qcur[j]=qnxt[j]; }
    }
    __syncthreads();
  }
}

// =====================================================================
// K3 v3: bf16 MFMA, all staging via global_load_lds from bf16 sources.
// =====================================================================
__global__ __launch_bounds__(256, 2) void k_final(
    const int* __restrict__ q_data, const uint16_t* __restrict__ q_bf,
    const uint16_t* __restrict__ reads16, const uint16_t* __restrict__ wr_bf,
    const float* __restrict__ br, const float* __restrict__ Wp,
    const float* __restrict__ bp, const float* __restrict__ target,
    float* __restrict__ out, float* __restrict__ parts)
{
  __shared__ uint16_t Ab[64*32];    // 4 KB
  __shared__ uint16_t Bb[128*32];   // 8 KB
  __shared__ float redbuf[8];
  const int tid = threadIdx.x;
  const int lane = tid & 63, wid = tid >> 6;
  const int rb = blockIdx.x * 64;

  const char* rdc = (const char*)reads16;
  const char* qbc = (const char*)q_bf;
  const char* wrc = (const char*)wr_bf;
  const int arow = wid*16 + (lane>>2);
  size_t aoff_r = (size_t)(rb+arow)*512 + (size_t)(lane&3)*16;
  size_t aoff_q = (size_t)q_data[rb+arow]*256 + (size_t)(lane&3)*16;
  size_t boff0  = (size_t)(wid*32 + (lane>>2))*768 + (size_t)(lane&3)*16;
  size_t boff1  = boff0 + 16*768;

  f32x4 acc[8];
  #pragma unroll
  for (int tj=0;tj<8;tj++) acc[tj] = (f32x4)(0.f);

  #pragma unroll 1
  for (int kc=0; kc<12; kc++){
    __syncthreads();
    if (kc < 8) gl_lds16(rdc + aoff_r + (size_t)kc*64,     &Ab[wid*512]);
    else        gl_lds16(qbc + aoff_q + (size_t)(kc-8)*64, &Ab[wid*512]);
    gl_lds16(wrc + boff0 + (size_t)kc*64, &Bb[(wid*2+0)*512]);
    gl_lds16(wrc + boff1 + (size_t)kc*64, &Bb[(wid*2+1)*512]);
    __syncthreads();
    bf16x8 af = *(const bf16x8*)&Ab[(wid*16 + (lane&15))*32 + (lane>>4)*8];
    #pragma unroll
    for (int tj=0;tj<8;tj++){
      bf16x8 bf = *(const bf16x8*)&Bb[(tj*16 + (lane&15))*32 + (lane>>4)*8];
      acc[tj] = __builtin_amdgcn_mfma_f32_16x16x32_bf16(af, bf, acc[tj], 0, 0, 0);
    }
  }
  const int cl = lane & 15, rq = lane >> 4;
  float p[4] = {0.f,0.f,0.f,0.f};
  #pragma unroll
  for (int tj=0;tj<8;tj++){
    int cg = tj*16 + cl;
    float brv = br[cg], wpv = Wp[cg];
    #pragma unroll
    for (int r=0;r<4;r++){
      float x = acc[tj][r] + brv;
      float hh = 1.f - 2.f/(__expf(2.f*x)+1.f);
      p[r] = fmaf(hh, wpv, p[r]);
    }
  }
  #pragma unroll
  for (int off=1; off<16; off<<=1){
    #pragma unroll
    for (int r=0;r<4;r++) p[r] += __shfl_xor(p[r], off);
  }
  float bpv = bp[0];
  float lsum = 0.f, csum = 0.f;
  if (cl == 0){
    #pragma unroll
    for (int r=0;r<4;r++){
      int row = rb + wid*16 + rq*4 + r;
      float pred = p[r] + bpv;
      out[1 + row] = 1.f/(1.f + __expf(-pred));
      float tg = target[row];
      if (tg >= 0.f){
        lsum += fmaxf(pred, 0.f) - pred*tg + log1pf(__expf(-fabsf(pred)));
        csum += 1.f;
      }
    }
  }
  #pragma unroll
  for (int off=16; off<64; off<<=1){
    lsum += __shfl_xor(lsum, off);
    csum += __shfl_xor(csum, off);
  }
  if (lane == 0){ redbuf[wid*2] = lsum; redbuf[wid*2+1] = csum; }
  __syncthreads();
  if (tid == 0){
    parts[blockIdx.x]        = redbuf[0]+redbuf[2]+redbuf[4]+redbuf[6];
    parts[2000 + blockIdx.x] = redbuf[1]+redbuf[3]+redbuf[5]+redbuf[7];
  }
}

// =====================================================================
// K4: final loss reduction (unchanged)
// =====================================================================
__global__ __launch_bounds__(256) void k_loss(
    const float* __restrict__ parts, float* __restrict__ out)
{
  __shared__ float red[8];
  const int tid = threadIdx.x;
  float l = 0.f, cn = 0.f;
  for (int i = tid; i < 2000; i += 256){ l += parts[i]; cn += parts[2000+i]; }
  #pragma unroll
  for (int off=32; off>0; off>>=1){ l += __shfl_xor(l, off); cn += __shfl_xor(cn, off); }
  if ((tid & 63) == 0){ red[(tid>>6)*2] = l; red[(tid>>6)*2+1] = cn; }
  __syncthreads();
  if (tid == 0){
    float L = red[0]+red[2]+red[4]+red[6];
    float C = red[1]+red[3]+red[5]+red[7];
    out[0] = L / fmaxf(C, 1.f);
  }
}

// =====================================================================
extern "C" void kernel_launch(void* const* d_in, const int* in_sizes, int n_in,
                              void* d_out, int out_size, void* d_ws, size_t ws_size,
                              hipStream_t stream) {
  const int*   q_data  = (const int*)d_in[0];
  const int*   qa_data = (const int*)d_in[1];
  const float* target  = (const float*)d_in[2];
  const float* q_tab   = (const float*)d_in[3];
  const float* qa_tab  = (const float*)d_in[4];
  const float* Mk  = (const float*)d_in[5];
  const float* Mv0 = (const float*)d_in[6];
  const float* We  = (const float*)d_in[7];
  const float* be  = (const float*)d_in[8];
  const float* Wa  = (const float*)d_in[9];
  const float* ba  = (const float*)d_in[10];
  const float* Wr  = (const float*)d_in[11];
  const float* br  = (const float*)d_in[12];
  const float* Wp  = (const float*)d_in[13];
  const float* bp  = (const float*)d_in[14];

  char* ws = (char*)d_ws;
  float*          w_ws     = (float*)ws;                           // [0, 26,624,000)
  __hip_bfloat16* ea_ws    = (__hip_bfloat16*)(ws + 26624000);     // 131,072,000 B
  uint16_t*       qa_bf    = (uint16_t*)(ws + 157696000);          // 51,200,512 B
  uint16_t*       wcomb    = (uint16_t*)(ws + 208896512);          // 262,144 B
  __hip_bfloat16* reads_ws = (__hip_bfloat16*)(ws + 157696000);    // 65,536,000 B (after k_ea)
  float*          parts    = (float*)ws;                           // 16,000 B (after k_scan)
  uint16_t*       q_bf     = (uint16_t*)(ws + 2000000);            // 12,800,256 B (after k_scan)
  uint16_t*       wr_bf    = (uint16_t*)(ws + 16000000);           // 98,304 B (after k_scan)

  float* out = (float*)d_out;   // f32: [loss, probs(128000)]

  k_w    <<<1000, 128, 0, stream>>>(q_data, q_tab, Mk, w_ws);
  k_cvt  <<<2048, 256, 0, stream>>>(qa_tab, We, Wa, qa_bf, wcomb);
  k_ea   <<<4000, 256, 0, stream>>>(qa_data, qa_bf, wcomb, be, ba, ea_ws);
  k_scan <<<256,  512, 0, stream>>>(q_data, w_ws, (const uint16_t*)ea_ws, Mv0, reads_ws);
  k_cvt2 <<<1024, 256, 0, stream>>>(q_tab, Wr, q_bf, wr_bf);
  k_final<<<2000, 256, 0, stream>>>(q_data, q_bf, (const uint16_t*)reads_ws, wr_bf, br, Wp, bp, target, out, parts);
  k_loss <<<1,    256, 0, stream>>>(parts, out);
}